// Round 2
// baseline (1095.076 us; speedup 1.0000x reference)
//
#include <hip/hip_runtime.h>

// ---- shapes (hard-coded to this problem) ----
#define TT 64
#define SLOT 320          // OUT + ACT
#define CONCAT 1536       // IN + 4*SLOT
#define ROWPAD 1544       // CONCAT + 8 bf16 pad

typedef __attribute__((ext_vector_type(8))) short bf16x8;
typedef __attribute__((ext_vector_type(4))) short short4v;
typedef __attribute__((ext_vector_type(4))) float float4v;

__device__ __forceinline__ short f2bf(float f) {
    union { float f; unsigned u; } v;
    v.f = f;
    unsigned r = v.u + 0x7fffu + ((v.u >> 16) & 1u);  // RNE
    return (short)(r >> 16);
}

// Repack W (256 x 1536 fp32) into bf16 MFMA-B-fragment order in d_ws:
// frag index = (tile tl 0..15)*48 + (kblock kb 0..47), then lane 0..63, then j 0..7.
// element = W[tl*16 + (lane&15)][kb*32 + (lane>>4)*8 + j]
// -> a wave's B-frag load for (tl,kb) is one fully-coalesced 1KB chunk.
__global__ void wprep_kernel(const float* __restrict__ W, short* __restrict__ Wb) {
    int idx = blockIdx.x * 256 + threadIdx.x;       // 0 .. 49151 (16*48*64)
    if (idx >= 16 * 48 * 64) return;
    int lane = idx & 63;
    int kb   = (idx >> 6) % 48;
    int tl   = idx / (48 * 64);
    int n = tl * 16 + (lane & 15);
    int k = kb * 32 + (lane >> 4) * 8;
    const float* src = W + (size_t)n * CONCAT + k;
    short4v s0, s1;
    s0.x = f2bf(src[0]); s0.y = f2bf(src[1]); s0.z = f2bf(src[2]); s0.w = f2bf(src[3]);
    s1.x = f2bf(src[4]); s1.y = f2bf(src[5]); s1.z = f2bf(src[6]); s1.w = f2bf(src[7]);
    short* dst = Wb + (size_t)idx * 8;
    *(short4v*)dst = s0;
    *(short4v*)(dst + 4) = s1;
}

// 64 WGs x 1024 threads (16 waves). WG owns 16 sequences (one batch b x 16 p).
// wave = (ng = w>>2: outputs ng*64..+63) x (kq = w&3: K-quarter of 1536).
// Per step: MFMA partial over K-quarter -> LDS partial[4][16][256] fp32 -> reduce.
__global__ __launch_bounds__(1024) void hist_kernel(
    const float* __restrict__ o,    // (B,T,P,256)
    const float* __restrict__ act,  // (B,T,P,64)
    const float* __restrict__ bias, // (256)
    const short* __restrict__ Wb,   // packed bf16 B-frags
    float* __restrict__ out)        // (B,T,P,256)
{
    __shared__ short x[16 * ROWPAD];            // 49408 B
    __shared__ float partial[4 * 16 * 256];     // 65536 B

    const int tid  = threadIdx.x;
    const int wave = tid >> 6;
    const int lane = tid & 63;
    const int q    = lane >> 4;
    const int ln   = lane & 15;
    const int ng   = wave >> 2;
    const int kq   = wave & 3;
    const int bb   = blockIdx.x >> 2;
    const int p0   = (blockIdx.x & 3) << 4;

    // zero history region (cols 0..1279) of every row
    for (int i = tid; i < 16 * 640; i += 1024) {
        int row = i / 640, c = i % 640;
        *(float*)&x[row * ROWPAD + c * 2] = 0.f;
    }

    // reduce-phase constants: thread handles (seq s = wave, outs n0..n0+3)
    const float4v bias4 = ((const float4v*)bias)[lane];
    const int s_red  = wave;
    const int n0     = lane << 2;

    const int arow = ln * ROWPAD + (q << 3);

    // B-frag base pointers for this wave's 4 tiles at its K-quarter start
    const short* wb0 = Wb + ((size_t)(((ng * 4 + 0) * 48 + kq * 12) * 64 + lane)) * 8;
    const short* wb1 = Wb + ((size_t)(((ng * 4 + 1) * 48 + kq * 12) * 64 + lane)) * 8;
    const short* wb2 = Wb + ((size_t)(((ng * 4 + 2) * 48 + kq * 12) * 64 + lane)) * 8;
    const short* wb3 = Wb + ((size_t)(((ng * 4 + 3) * 48 + kq * 12) * 64 + lane)) * 8;

    for (int t = 0; t < TT; ++t) {
        const size_t tok = ((size_t)bb * TT + t) * 64 + p0;

        // ---- stage o_t into LDS x[.., 1280..1535] (bf16); a_t into a register ----
        {
            float4v ov = ((const float4v*)(o + tok * 256))[tid];
            int row = tid >> 6, col = (tid & 63) << 2;
            short4v s;
            s.x = f2bf(ov.x); s.y = f2bf(ov.y); s.z = f2bf(ov.z); s.w = f2bf(ov.w);
            *(short4v*)&x[row * ROWPAD + 1280 + col] = s;
        }
        float aval = (act + tok * 64)[tid];

        __syncthreads();   // o_t + prev-step slot writes visible to all

        // ---- MFMA over this wave's K-quarter ----
        float4v acc0 = {0.f, 0.f, 0.f, 0.f};
        float4v acc1 = acc0, acc2 = acc0, acc3 = acc0;
#pragma unroll
        for (int j = 0; j < 12; ++j) {
            const int kb = kq * 12 + j;
            int cL;
            if (kb < 40) {
                const int h   = kb / 10;
                const int r   = kb % 10;
                const int off = (r < 8) ? (r << 5) : (256 + ((r - 8) << 5));
                cL = (((h + t) & 3) * SLOT) + off;
            } else {
                cL = 1280 + ((kb - 40) << 5);
            }
            bf16x8 af = *(const bf16x8*)&x[arow + cL];
            bf16x8 b0 = *(const bf16x8*)(wb0 + (size_t)j * 512);
            bf16x8 b1 = *(const bf16x8*)(wb1 + (size_t)j * 512);
            bf16x8 b2 = *(const bf16x8*)(wb2 + (size_t)j * 512);
            bf16x8 b3 = *(const bf16x8*)(wb3 + (size_t)j * 512);
            acc0 = __builtin_amdgcn_mfma_f32_16x16x32_bf16(af, b0, acc0, 0, 0, 0);
            acc1 = __builtin_amdgcn_mfma_f32_16x16x32_bf16(af, b1, acc1, 0, 0, 0);
            acc2 = __builtin_amdgcn_mfma_f32_16x16x32_bf16(af, b2, acc2, 0, 0, 0);
            acc3 = __builtin_amdgcn_mfma_f32_16x16x32_bf16(af, b3, acc3, 0, 0, 0);
        }

        // ---- write K-quarter partials ----
        {
            float4v accs[4] = {acc0, acc1, acc2, acc3};
#pragma unroll
            for (int tl = 0; tl < 4; ++tl) {
#pragma unroll
                for (int r = 0; r < 4; ++r) {
                    const int seq = (q << 2) + r;           // C/D row
                    const int n   = (ng << 6) + (tl << 4) + ln;
                    partial[(kq * 16 + seq) * 256 + n] = accs[tl][r];
                }
            }
        }
        __syncthreads();   // partials complete; all slot reads complete

        // ---- reduce + epilogue: z -> global fp32, z/a -> LDS slot (t&3) bf16 ----
        {
            float4v z = bias4;
#pragma unroll
            for (int k = 0; k < 4; ++k) {
                float4v p = *(const float4v*)&partial[(k * 16 + s_red) * 256 + n0];
                z.x += p.x; z.y += p.y; z.z += p.z; z.w += p.w;
            }
            ((float4v*)(out + tok * 256))[tid] = z;
            const int pz = (t & 3) * SLOT;
            short4v s;
            s.x = f2bf(z.x); s.y = f2bf(z.y); s.z = f2bf(z.z); s.w = f2bf(z.w);
            *(short4v*)&x[s_red * ROWPAD + pz + n0] = s;
            x[s_red * ROWPAD + pz + 256 + (tid & 63)] = f2bf(aval);
        }
        // next iteration's first __syncthreads() orders slot writes vs MFMA reads
    }
}

extern "C" void kernel_launch(void* const* d_in, const int* in_sizes, int n_in,
                              void* d_out, int out_size, void* d_ws, size_t ws_size,
                              hipStream_t stream) {
    const float* o  = (const float*)d_in[0];
    const float* a  = (const float*)d_in[1];
    const float* W  = (const float*)d_in[2];
    const float* b  = (const float*)d_in[3];
    short* Wb = (short*)d_ws;   // 786432 B used

    hipLaunchKernelGGL(wprep_kernel, dim3(192), dim3(256), 0, stream, W, Wb);
    hipLaunchKernelGGL(hist_kernel, dim3(64), dim3(1024), 0, stream,
                       o, a, b, Wb, (float*)d_out);
}

// Round 3
// 615.631 us; speedup vs baseline: 1.7788x; 1.7788x over previous
//
#include <hip/hip_runtime.h>

// ---- shapes (hard-coded to this problem) ----
#define TT 64
#define SLOT 320          // OUT + ACT
#define CONCAT 1536       // IN + 4*SLOT
#define ROWPAD 1544       // CONCAT + 8 bf16 pad
#define XSHORTS (16 * ROWPAD)        // 24704 shorts = 49408 B
#define RINGS 3072                   // ring shorts per wave (6 slots x 512)

typedef __attribute__((ext_vector_type(8))) short bf16x8;
typedef __attribute__((ext_vector_type(4))) short short4v;
typedef __attribute__((ext_vector_type(4))) float float4v;

__device__ __forceinline__ short f2bf(float f) {
    union { float f; unsigned u; } v;
    v.f = f;
    unsigned r = v.u + 0x7fffu + ((v.u >> 16) & 1u);  // RNE
    return (short)(r >> 16);
}

// Repack W (256 x 1536 fp32) -> bf16 MFMA-B-fragment order:
// frag (tl 0..15, kb 0..47): lane L holds W[tl*16 + (L&15)][kb*32 + (L>>4)*8 + j], j=0..7.
// Wave tl's 48 frags are one contiguous 48KB stream.
__global__ void wprep_kernel(const float* __restrict__ W, short* __restrict__ Wb) {
    int idx = blockIdx.x * 256 + threadIdx.x;       // 0 .. 49151 (16*48*64)
    if (idx >= 16 * 48 * 64) return;
    int lane = idx & 63;
    int kb   = (idx >> 6) % 48;
    int tl   = idx / (48 * 64);
    int n = tl * 16 + (lane & 15);
    int k = kb * 32 + (lane >> 4) * 8;
    const float* src = W + (size_t)n * CONCAT + k;
    short4v s0, s1;
    s0.x = f2bf(src[0]); s0.y = f2bf(src[1]); s0.z = f2bf(src[2]); s0.w = f2bf(src[3]);
    s1.x = f2bf(src[4]); s1.y = f2bf(src[5]); s1.z = f2bf(src[6]); s1.w = f2bf(src[7]);
    short* dst = Wb + (size_t)idx * 8;
    *(short4v*)dst = s0;
    *(short4v*)(dst + 4) = s1;
}

// address-space cast helpers for global_load_lds
typedef const __attribute__((address_space(1))) unsigned int* gas_t;
typedef __attribute__((address_space(3))) unsigned int* las_t;

// s_waitcnt immediates (gfx9 encoding): vmcnt[3:0|15:14], exp[6:4], lgkm[11:8]
#define WAIT_VM(n)   __builtin_amdgcn_s_waitcnt(0x0F70 | (n))   // vmcnt<=n, lgkm/exp free
#define WAIT_LGKM0() __builtin_amdgcn_s_waitcnt(0xC07F)         // lgkmcnt(0), vmcnt free

// 64 WGs x 1024 threads (16 waves), 16 seqs/WG. Wave w owns out-tile w (16 outs),
// full K=1536 -> no cross-wave reduction. W streamed via per-wave-private 6-slot
// DMA ring in LDS (global_load_lds, 16B/lane) -> deep async queue, no K-loop barriers.
__global__ __launch_bounds__(1024) void hist_kernel(
    const float* __restrict__ o,    // (B,T,P,256)
    const float* __restrict__ act,  // (B,T,P,64)
    const float* __restrict__ bias, // (256)
    const short* __restrict__ Wb,   // packed bf16 B-frags, [tl][kb][lane][8]
    float* __restrict__ out)        // (B,T,P,256)
{
    __shared__ short lds[XSHORTS + 16 * RINGS];   // 49408 + 98304 = 147712 B

    const int tid  = threadIdx.x;
    const int wave = tid >> 6;
    const int lane = tid & 63;
    const int q    = lane >> 4;
    const int ln   = lane & 15;
    const int bb   = blockIdx.x >> 2;
    const int p0   = (blockIdx.x & 3) << 4;

    short* ring = lds + XSHORTS + wave * RINGS;          // this wave's ring
    const short* wsrc = Wb + (size_t)wave * 48 * 512;    // contiguous 48KB W slice

    // zero z/a history (cols 0..1279 of each seq row)
    for (int i = tid; i < 16 * 640; i += 1024) {
        int row = i / 640, c = i % 640;
        *(float*)&lds[row * ROWPAD + c * 2] = 0.f;
    }

    const float bv = bias[wave * 16 + ln];
    const int arow = ln * ROWPAD + (q << 3);

#define DMA(kb) __builtin_amdgcn_global_load_lds( \
        (gas_t)(const void*)(wsrc + (kb) * 512 + lane * 8), \
        (las_t)(void*)(ring + ((kb) % 6) * 512), 16, 0, 0)

// logical W column kb -> physical LDS column (history slots rotate with t)
#define CLCOL(kb) ((kb) < 40 \
        ? pbase[(kb) / 10] + (((kb) % 10) < 8 ? (((kb) % 10) << 5) : (256 + ((((kb) % 10) - 8) << 5))) \
        : 1280 + (((kb) - 40) << 5))

#define PAIR(J, WN) { \
        WAIT_VM(WN); \
        bf16x8 bf0 = *(const bf16x8*)(ring + ((2*(J)) % 6) * 512 + lane * 8); \
        bf16x8 bf1 = *(const bf16x8*)(ring + ((2*(J)+1) % 6) * 512 + lane * 8); \
        bf16x8 af0 = *(const bf16x8*)&lds[arow + CLCOL(2*(J))]; \
        bf16x8 af1 = *(const bf16x8*)&lds[arow + CLCOL(2*(J)+1)]; \
        WAIT_LGKM0(); \
        acc_e = __builtin_amdgcn_mfma_f32_16x16x32_bf16(af0, bf0, acc_e, 0, 0, 0); \
        acc_o = __builtin_amdgcn_mfma_f32_16x16x32_bf16(af1, bf1, acc_o, 0, 0, 0); \
        if (2*(J) + 6 < 48) { DMA(2*(J)+6); DMA(2*(J)+7); } \
    }

    for (int t = 0; t < TT; ++t) {
        const size_t tok = ((size_t)bb * TT + t) * 64 + p0;

        // stage o_t -> x o-region (bf16); a_t -> register
        {
            float4v ov = ((const float4v*)(o + tok * 256))[tid];
            int row = tid >> 6, col = (tid & 63) << 2;
            short4v s;
            s.x = f2bf(ov.x); s.y = f2bf(ov.y); s.z = f2bf(ov.z); s.w = f2bf(ov.w);
            *(short4v*)&lds[row * ROWPAD + 1280 + col] = s;
        }
        float aval = (act + tok * 64)[tid];

        __syncthreads();   // barrier alpha: o-region + prev-step z/a slot visible
                           // (also drains prior stores/o-loads -> vmcnt==0 here)

        int pbase[4];
#pragma unroll
        for (int h = 0; h < 4; ++h) pbase[h] = ((h + t) & 3) * SLOT;

        float4v acc_e = {0.f, 0.f, 0.f, 0.f};
        float4v acc_o = acc_e;

        // prime the ring (6 frags in flight), then paced K-loop: no barriers inside
        DMA(0); DMA(1); DMA(2); DMA(3); DMA(4); DMA(5);
        PAIR(0, 4)  PAIR(1, 4)  PAIR(2, 4)  PAIR(3, 4)  PAIR(4, 4)  PAIR(5, 4)
        PAIR(6, 4)  PAIR(7, 4)  PAIR(8, 4)  PAIR(9, 4)  PAIR(10, 4) PAIR(11, 4)
        PAIR(12, 4) PAIR(13, 4) PAIR(14, 4) PAIR(15, 4) PAIR(16, 4) PAIR(17, 4)
        PAIR(18, 4) PAIR(19, 4) PAIR(20, 4) PAIR(21, 4) PAIR(22, 2) PAIR(23, 0)

        __syncthreads();   // barrier beta: all A-reads done -> safe to overwrite slot t&3

        // epilogue: z -> global fp32; z,a -> LDS slot (t&3) as bf16
        const int pz = (t & 3) * SLOT;
        float* outp = out + tok * 256;
        float4v ze = acc_e, zo = acc_o;
#pragma unroll
        for (int r = 0; r < 4; ++r) {
            const int m = (q << 2) + r;               // C/D: row m = quad*4+reg (seq)
            const int n = (wave << 4) + ln;           // out index
            float z = ze[r] + zo[r] + bv;
            outp[(size_t)m * 256 + n] = z;
            lds[m * ROWPAD + pz + n] = f2bf(z);
        }
        lds[(tid >> 6) * ROWPAD + pz + 256 + (tid & 63)] = f2bf(aval);
        // next iteration's barrier alpha orders these writes before the next MFMA phase
    }
#undef PAIR
#undef CLCOL
#undef DMA
}

extern "C" void kernel_launch(void* const* d_in, const int* in_sizes, int n_in,
                              void* d_out, int out_size, void* d_ws, size_t ws_size,
                              hipStream_t stream) {
    const float* o  = (const float*)d_in[0];
    const float* a  = (const float*)d_in[1];
    const float* W  = (const float*)d_in[2];
    const float* b  = (const float*)d_in[3];
    short* Wb = (short*)d_ws;   // 786432 B used

    hipLaunchKernelGGL(wprep_kernel, dim3(192), dim3(256), 0, stream, W, Wb);
    hipLaunchKernelGGL(hist_kernel, dim3(64), dim3(1024), 0, stream,
                       o, a, b, Wb, (float*)d_out);
}